// Round 3
// baseline (288.883 us; speedup 1.0000x reference)
//
#include <hip/hip_runtime.h>

#define NROWS 8192
#define DIM   1024
#define EPSF  1e-8f

typedef __attribute__((ext_vector_type(4))) float f32x4;
typedef __attribute__((ext_vector_type(8))) short bf16x8;

typedef __attribute__((address_space(1))) void g_void;
typedef __attribute__((address_space(3))) void l_void;

__device__ __forceinline__ void async_copy16(void* lds, const void* g) {
  __builtin_amdgcn_global_load_lds((g_void*)const_cast<void*>(g), (l_void*)lds, 16, 0, 0);
}

__device__ __forceinline__ unsigned short f2bf(float f) {
  union { float f; unsigned u; } c; c.f = f;
  unsigned u = c.u;
  u += 0x7FFFu + ((u >> 16) & 1u);   // round-to-nearest-even
  return (unsigned short)(u >> 16);
}

__device__ __forceinline__ unsigned encf(float f) {
  const unsigned bits = __float_as_uint(f);
  return (bits & 0x80000000u) ? ~bits : (bits | 0x80000000u);
}

template<int N> __device__ __forceinline__ void vmwait() {
  if constexpr (N == 6)      asm volatile("s_waitcnt vmcnt(6)" ::: "memory");
  else if constexpr (N == 4) asm volatile("s_waitcnt vmcnt(4)" ::: "memory");
  else if constexpr (N == 2) asm volatile("s_waitcnt vmcnt(2)" ::: "memory");
  else                       asm volatile("s_waitcnt vmcnt(0)" ::: "memory");
}
__device__ __forceinline__ void barf() {
  __builtin_amdgcn_s_barrier();
  asm volatile("" ::: "memory");
}

// ---------------- Kernel A: row L2-normalize, cast to bf16, init maxenc ----------------
extern "C" __global__ __launch_bounds__(256)
void koleo_norm(const float* __restrict__ in, unsigned short* __restrict__ xb,
                unsigned* __restrict__ maxenc) {
  const int row = blockIdx.x;
  const int tid = threadIdx.x;
  const float4 v = reinterpret_cast<const float4*>(in + (size_t)row * DIM)[tid];
  float ss = v.x * v.x + v.y * v.y + v.z * v.z + v.w * v.w;
#pragma unroll
  for (int off = 32; off > 0; off >>= 1) ss += __shfl_down(ss, off);
  __shared__ float wsum[4];
  if ((tid & 63) == 0) wsum[tid >> 6] = ss;
  __syncthreads();
  const float total = wsum[0] + wsum[1] + wsum[2] + wsum[3];
  const float scale = 1.0f / (sqrtf(total) + EPSF);
  ushort4 o;
  o.x = f2bf(v.x * scale); o.y = f2bf(v.y * scale);
  o.z = f2bf(v.z * scale); o.w = f2bf(v.w * scale);
  reinterpret_cast<ushort4*>(xb + (size_t)row * DIM)[tid] = o;
  if (row < NROWS / 256) maxenc[row * 256 + tid] = 0u;  // enc(any real dot) > 0
}

// ---------------- Kernel B: upper-triangle Gram-max, 256x256 tile, 8-phase pipeline ----------------
#define BM 256
#define BK 64
#define NT (NROWS / BM)            // 32 tiles per dim
#define NBLK (NT * (NT + 1) / 2)   // 528 upper-triangle blocks
#define NKT (DIM / BK)             // 16 K-tiles

// stage one 16KB chunk (128 rows x 128B), XOR-swizzled source so LDS holds
// LDS[o] = logical[o ^ ((row&7)<<4)] with linear gload_lds destination
__device__ __forceinline__ void stage_chunk(char* dst, const char* gbase, int ktile, int tid) {
#pragma unroll
  for (int l = 0; l < 2; ++l) {
    const int o  = l * 8192 + tid * 16;
    const int so = o ^ (((o >> 7) & 7) << 4);
    async_copy16(dst + o, gbase + (size_t)(so >> 7) * 2048 + ktile * 128 + (so & 127));
  }
}

#define MFMAQ(MH, NH)                                                                 \
  {                                                                                   \
    _Pragma("unroll")                                                                 \
    for (int kk = 0; kk < 2; ++kk)                                                    \
      _Pragma("unroll")                                                               \
      for (int m = 0; m < 4; ++m)                                                     \
        _Pragma("unroll")                                                             \
        for (int n = 0; n < 2; ++n)                                                   \
          acc[(MH)*4 + m][(NH)*2 + n] = __builtin_amdgcn_mfma_f32_16x16x32_bf16(      \
              aF[(MH)*4 + m][kk], bF[(NH)*2 + n][kk], acc[(MH)*4 + m][(NH)*2 + n],    \
              0, 0, 0);                                                               \
  }

// one K-tile = 4 phases. Reads from Lc, stages B(t+1) into Ln (q0,q1) and A(t+2)
// into Lc (q2,q3). vmcnt(6) steady-state: worst chunk B-h1(t) issued at (t-1,q1)
// has exactly 6 newer loads at the (t,q0) barrier.
template<bool SB, bool SA, int V0, int V1, int V2, int V3>
__device__ __forceinline__ void ktile(int t, char* Lc, char* Ln,
    const char* gA0, const char* gA1, const char* gB0, const char* gB1,
    int tid, int lane, int wr, int wc,
    bf16x8 (&aF)[8][2], bf16x8 (&bF)[4][2], f32x4 (&acc)[8][4]) {
  const int lr = lane & 15, lg = lane >> 4;
  const int xr = (lane & 7) << 4;
  // ---- q0: read a[0..3], b[0..1]; stage B-h0(t+1) ----
#pragma unroll
  for (int m = 0; m < 4; ++m)
#pragma unroll
    for (int kk = 0; kk < 2; ++kk)
      aF[m][kk] = *(const bf16x8*)(Lc + (((wr * 128 + m * 16 + lr) * 128 + kk * 64 + lg * 16) ^ xr));
#pragma unroll
  for (int n = 0; n < 2; ++n)
#pragma unroll
    for (int kk = 0; kk < 2; ++kk)
      bF[n][kk] = *(const bf16x8*)(Lc + 32768 + (((wc * 64 + n * 16 + lr) * 128 + kk * 64 + lg * 16) ^ xr));
  if constexpr (SB) stage_chunk(Ln + 32768, gB0, t + 1, tid);
  vmwait<V0>(); barf();
  __builtin_amdgcn_s_setprio(1); MFMAQ(0, 0); __builtin_amdgcn_s_setprio(0);
  // ---- q1: read a[4..7], b[2..3]; stage B-h1(t+1) ----
#pragma unroll
  for (int m = 4; m < 8; ++m)
#pragma unroll
    for (int kk = 0; kk < 2; ++kk)
      aF[m][kk] = *(const bf16x8*)(Lc + (((wr * 128 + m * 16 + lr) * 128 + kk * 64 + lg * 16) ^ xr));
#pragma unroll
  for (int n = 2; n < 4; ++n)
#pragma unroll
    for (int kk = 0; kk < 2; ++kk)
      bF[n][kk] = *(const bf16x8*)(Lc + 32768 + (((wc * 64 + n * 16 + lr) * 128 + kk * 64 + lg * 16) ^ xr));
  if constexpr (SB) stage_chunk(Ln + 49152, gB1, t + 1, tid);
  vmwait<V1>(); barf();
  __builtin_amdgcn_s_setprio(1); MFMAQ(0, 1); __builtin_amdgcn_s_setprio(0);
  // ---- q2: stage A-h0(t+2) (A(t) reads finished at q1) ----
  if constexpr (SA) stage_chunk(Lc, gA0, t + 2, tid);
  vmwait<V2>(); barf();
  __builtin_amdgcn_s_setprio(1); MFMAQ(1, 0); __builtin_amdgcn_s_setprio(0);
  // ---- q3: stage A-h1(t+2) ----
  if constexpr (SA) stage_chunk(Lc + 16384, gA1, t + 2, tid);
  vmwait<V3>(); barf();
  __builtin_amdgcn_s_setprio(1); MFMAQ(1, 1); __builtin_amdgcn_s_setprio(0);
}

extern "C" __global__ __launch_bounds__(512, 2)
void koleo_grammax(const unsigned short* __restrict__ xb, unsigned* __restrict__ maxenc) {
  __shared__ char lds[131072];   // 2 dbuf x (A 32KB + B 32KB)

  const int tid  = threadIdx.x;
  const int lane = tid & 63;
  const int wid  = tid >> 6;
  const int wr   = wid >> 2;     // 0..1: rows wr*128..+127
  const int wc   = wid & 3;      // 0..3: cols wc*64..+63
  const int lr   = lane & 15;
  const int lg   = lane >> 4;

  // XCD-aware bijective swizzle (528 % 8 == 0)
  const int bid = (blockIdx.x % 8) * (NBLK / 8) + blockIdx.x / 8;
  // upper-triangle decode (ti <= tj)
  int ti = (int)((2.0f * NT + 1.0f -
                  sqrtf((float)((2 * NT + 1) * (2 * NT + 1) - 8 * bid))) * 0.5f);
  while ((ti + 1) * NT - ((ti + 1) * ti) / 2 <= bid) ++ti;
  while (ti * NT - (ti * (ti - 1)) / 2 > bid) --ti;
  const int tj = ti + (bid - (ti * NT - (ti * (ti - 1)) / 2));

  const int rowBase = ti * BM;
  const int colBase = tj * BM;
  const bool diag = (ti == tj);

  const char* xbb = (const char*)xb;
  const char* gA0 = xbb + (size_t)rowBase * 2048;
  const char* gA1 = xbb + (size_t)(rowBase + 128) * 2048;
  const char* gB0 = xbb + (size_t)colBase * 2048;
  const char* gB1 = xbb + (size_t)(colBase + 128) * 2048;
  char* L0 = lds;
  char* L1 = lds + 65536;

  f32x4  acc[8][4] = {};
  bf16x8 aF[8][2];
  bf16x8 bF[4][2];

  // prologue: issue order defines the vmcnt arithmetic
  stage_chunk(L0,         gA0, 0, tid);
  stage_chunk(L0 + 16384, gA1, 0, tid);
  stage_chunk(L0 + 32768, gB0, 0, tid);
  stage_chunk(L0 + 49152, gB1, 0, tid);
  stage_chunk(L1,         gA0, 1, tid);
  stage_chunk(L1 + 16384, gA1, 1, tid);
  vmwait<4>();   // all of K-tile 0 complete (4 newest = A-h(1) pair)
  barf();

#pragma unroll 1
  for (int t2 = 0; t2 < 14; t2 += 2) {
    ktile<true, true, 6, 6, 6, 6>(t2,     L0, L1, gA0, gA1, gB0, gB1, tid, lane, wr, wc, aF, bF, acc);
    ktile<true, true, 6, 6, 6, 6>(t2 + 1, L1, L0, gA0, gA1, gB0, gB1, tid, lane, wr, wc, aF, bF, acc);
  }
  // tail: t=14 stages only B(15); t=15 stages nothing
  ktile<true,  false, 6, 6, 6, 2>(14, L0, L1, gA0, gA1, gB0, gB1, tid, lane, wr, wc, aF, bF, acc);
  ktile<false, false, 0, 0, 0, 0>(15, L1, L0, gA0, gA1, gB0, gB1, tid, lane, wr, wc, aF, bF, acc);

  // ---- epilogue: per-row / per-col max with diagonal mask ----
  __syncthreads();                      // full drain; LDS reused below
  unsigned* smaxr = (unsigned*)lds;           // [256]
  unsigned* smaxc = (unsigned*)(lds + 1024);  // [256]
  if (tid < 256) { smaxr[tid] = 0u; smaxc[tid] = 0u; }
  __syncthreads();

#pragma unroll
  for (int m = 0; m < 8; ++m) {
#pragma unroll
    for (int r = 0; r < 4; ++r) {
      const int lrow = wr * 128 + m * 16 + lg * 4 + r;  // C/D: row=(lane>>4)*4+reg
      const int grow = rowBase + lrow;
      float mx = -2.0f;
#pragma unroll
      for (int n = 0; n < 4; ++n) {
        float v = acc[m][n][r];
        const int gcol = colBase + wc * 64 + n * 16 + lr;  // C/D: col=lane&15
        if (grow == gcol) v = -2.0f;                        // mask self-similarity
        mx = fmaxf(mx, v);
      }
#pragma unroll
      for (int off = 1; off < 16; off <<= 1) mx = fmaxf(mx, __shfl_xor(mx, off));
      if (lr == 0) atomicMax(&smaxr[lrow], encf(mx));
    }
  }
  if (!diag) {  // off-diagonal tiles: rows/cols disjoint, no mask needed
#pragma unroll
    for (int n = 0; n < 4; ++n) {
      const int lcol = wc * 64 + n * 16 + lr;
      float mx = -2.0f;
#pragma unroll
      for (int m = 0; m < 8; ++m)
#pragma unroll
        for (int r = 0; r < 4; ++r) mx = fmaxf(mx, acc[m][n][r]);
      mx = fmaxf(mx, __shfl_xor(mx, 16));
      mx = fmaxf(mx, __shfl_xor(mx, 32));
      if (lg == 0) atomicMax(&smaxc[lcol], encf(mx));
    }
  }
  __syncthreads();
  if (tid < 256) {
    atomicMax(&maxenc[rowBase + tid], smaxr[tid]);
    if (!diag) atomicMax(&maxenc[colBase + tid], smaxc[tid]);
  }
}

// ---------------- Kernel C: loss reduction ----------------
extern "C" __global__ __launch_bounds__(256)
void koleo_loss(const unsigned* __restrict__ maxenc, float* __restrict__ out) {
  const int tid = threadIdx.x;
  float sum = 0.0f;
  for (int i = tid; i < NROWS; i += 256) {
    const unsigned u    = maxenc[i];
    const unsigned bits = (u & 0x80000000u) ? (u & 0x7FFFFFFFu) : ~u;
    const float m = __uint_as_float(bits);
    const float d = sqrtf(fmaxf(2.0f - 2.0f * m, 0.0f)) + EPSF;  // ||x_i - x_nn|| + eps
    sum += logf(d + EPSF);
  }
#pragma unroll
  for (int off = 32; off > 0; off >>= 1) sum += __shfl_down(sum, off);
  __shared__ float wsum[4];
  if ((tid & 63) == 0) wsum[tid >> 6] = sum;
  __syncthreads();
  if (tid == 0) out[0] = -(wsum[0] + wsum[1] + wsum[2] + wsum[3]) / (float)NROWS;
}

extern "C" void kernel_launch(void* const* d_in, const int* in_sizes, int n_in,
                              void* d_out, int out_size, void* d_ws, size_t ws_size,
                              hipStream_t stream) {
  const float* in = (const float*)d_in[0];
  unsigned short* xb = (unsigned short*)d_ws;                                  // 16 MB bf16 x
  unsigned* maxenc   = (unsigned*)((char*)d_ws + (size_t)NROWS * DIM * 2);     // 32 KB
  float* out = (float*)d_out;

  hipLaunchKernelGGL(koleo_norm,    dim3(NROWS), dim3(256), 0, stream, in, xb, maxenc);
  hipLaunchKernelGGL(koleo_grammax, dim3(NBLK),  dim3(512), 0, stream, xb, maxenc);
  hipLaunchKernelGGL(koleo_loss,    dim3(1),     dim3(256), 0, stream, maxenc, out);
}

// Round 4
// 238.918 us; speedup vs baseline: 1.2091x; 1.2091x over previous
//
#include <hip/hip_runtime.h>

#define NROWS 8192
#define DIM   1024
#define EPSF  1e-8f

typedef __attribute__((ext_vector_type(4))) float f32x4;
typedef __attribute__((ext_vector_type(8))) short bf16x8;

typedef __attribute__((address_space(1))) void g_void;
typedef __attribute__((address_space(3))) void l_void;

__device__ __forceinline__ void async_copy16(void* lds, const void* g) {
  __builtin_amdgcn_global_load_lds((g_void*)const_cast<void*>(g), (l_void*)lds, 16, 0, 0);
}

__device__ __forceinline__ unsigned short f2bf(float f) {
  union { float f; unsigned u; } c; c.f = f;
  unsigned u = c.u;
  u += 0x7FFFu + ((u >> 16) & 1u);   // round-to-nearest-even
  return (unsigned short)(u >> 16);
}

__device__ __forceinline__ unsigned encf(float f) {
  const unsigned bits = __float_as_uint(f);
  return (bits & 0x80000000u) ? ~bits : (bits | 0x80000000u);
}

template<int N> __device__ __forceinline__ void vmwait() {
  if constexpr (N == 6)      asm volatile("s_waitcnt vmcnt(6)" ::: "memory");
  else if constexpr (N == 4) asm volatile("s_waitcnt vmcnt(4)" ::: "memory");
  else if constexpr (N == 2) asm volatile("s_waitcnt vmcnt(2)" ::: "memory");
  else                       asm volatile("s_waitcnt vmcnt(0)" ::: "memory");
}
__device__ __forceinline__ void barf() {
  __builtin_amdgcn_s_barrier();
  asm volatile("" ::: "memory");
}

// ---------------- Kernel A: row L2-normalize, cast to bf16, init maxenc ----------------
extern "C" __global__ __launch_bounds__(256)
void koleo_norm(const float* __restrict__ in, unsigned short* __restrict__ xb,
                unsigned* __restrict__ maxenc) {
  const int row = blockIdx.x;
  const int tid = threadIdx.x;
  const float4 v = reinterpret_cast<const float4*>(in + (size_t)row * DIM)[tid];
  float ss = v.x * v.x + v.y * v.y + v.z * v.z + v.w * v.w;
#pragma unroll
  for (int off = 32; off > 0; off >>= 1) ss += __shfl_down(ss, off);
  __shared__ float wsum[4];
  if ((tid & 63) == 0) wsum[tid >> 6] = ss;
  __syncthreads();
  const float total = wsum[0] + wsum[1] + wsum[2] + wsum[3];
  const float scale = 1.0f / (sqrtf(total) + EPSF);
  ushort4 o;
  o.x = f2bf(v.x * scale); o.y = f2bf(v.y * scale);
  o.z = f2bf(v.z * scale); o.w = f2bf(v.w * scale);
  reinterpret_cast<ushort4*>(xb + (size_t)row * DIM)[tid] = o;
  if (row < NROWS / 256) maxenc[row * 256 + tid] = 0u;  // enc(any real dot) > 0
}

// ---------------- Kernel B: upper-triangle Gram-max, 256x256 tile, 8-phase pipeline ----------------
#define BM 256
#define BK 64
#define NT (NROWS / BM)            // 32 tiles per dim
#define NBLK (NT * (NT + 1) / 2)   // 528 upper-triangle blocks
#define NKT (DIM / BK)             // 16 K-tiles

// stage one 16KB chunk (128 rows x 128B), XOR-swizzled source so LDS holds
// LDS[o] = logical[o ^ ((row&7)<<4)] with linear gload_lds destination
__device__ __forceinline__ void stage_chunk(char* dst, const char* gbase, int ktile, int tid) {
#pragma unroll
  for (int l = 0; l < 2; ++l) {
    const int o  = l * 8192 + tid * 16;
    const int so = o ^ (((o >> 7) & 7) << 4);
    async_copy16(dst + o, gbase + (size_t)(so >> 7) * 2048 + ktile * 128 + (so & 127));
  }
}

// bF holds only the CURRENT n-pair (re-read per phase): 16 VGPR live, not 32
#define MFMAQ(MH, NH)                                                                 \
  {                                                                                   \
    _Pragma("unroll")                                                                 \
    for (int kk = 0; kk < 2; ++kk)                                                    \
      _Pragma("unroll")                                                               \
      for (int m = 0; m < 4; ++m)                                                     \
        _Pragma("unroll")                                                             \
        for (int n = 0; n < 2; ++n)                                                   \
          acc[(MH)*4 + m][(NH)*2 + n] = __builtin_amdgcn_mfma_f32_16x16x32_bf16(      \
              aF[(MH)*4 + m][kk], bF[n][kk], acc[(MH)*4 + m][(NH)*2 + n],             \
              0, 0, 0);                                                               \
  }

#define READ_B(NH)                                                                    \
  _Pragma("unroll")                                                                   \
  for (int n = 0; n < 2; ++n)                                                         \
    _Pragma("unroll")                                                                 \
    for (int kk = 0; kk < 2; ++kk)                                                    \
      bF[n][kk] = *(const bf16x8*)(Lc + 32768 +                                       \
          (((wc * 64 + ((NH)*2 + n) * 16 + lr) * 128 + kk * 64 + lg * 16) ^ xr));

// one K-tile = 4 phases. All Lc A-region reads complete by q1; stages into Lc
// A-region happen q2/q3 (barrier-separated). B-region of Lc is never a stage
// destination, so q2/q3 may re-read it freely. vmcnt(6) steady-state: worst
// chunk B-h1(t) issued at (t-1,q1) has exactly 6 newer loads at the (t,q0) barrier.
template<bool SB, bool SA, int V0, int V1, int V2, int V3>
__device__ __forceinline__ void ktile(int t, char* Lc, char* Ln,
    const char* gA0, const char* gA1, const char* gB0, const char* gB1,
    int tid, int lane, int wr, int wc,
    bf16x8 (&aF)[8][2], bf16x8 (&bF)[2][2], f32x4 (&acc)[8][4]) {
  const int lr = lane & 15, lg = lane >> 4;
  const int xr = (lane & 7) << 4;
  // ---- q0: read a[0..3] + b-pair0; stage B-h0(t+1) ----
#pragma unroll
  for (int m = 0; m < 4; ++m)
#pragma unroll
    for (int kk = 0; kk < 2; ++kk)
      aF[m][kk] = *(const bf16x8*)(Lc + (((wr * 128 + m * 16 + lr) * 128 + kk * 64 + lg * 16) ^ xr));
  READ_B(0);
  if constexpr (SB) stage_chunk(Ln + 32768, gB0, t + 1, tid);
  vmwait<V0>(); barf();
  __builtin_amdgcn_s_setprio(1); MFMAQ(0, 0); __builtin_amdgcn_s_setprio(0);
  // ---- q1: read a[4..7] + b-pair1; stage B-h1(t+1) ----
#pragma unroll
  for (int m = 4; m < 8; ++m)
#pragma unroll
    for (int kk = 0; kk < 2; ++kk)
      aF[m][kk] = *(const bf16x8*)(Lc + (((wr * 128 + m * 16 + lr) * 128 + kk * 64 + lg * 16) ^ xr));
  READ_B(1);
  if constexpr (SB) stage_chunk(Ln + 49152, gB1, t + 1, tid);
  vmwait<V1>(); barf();
  __builtin_amdgcn_s_setprio(1); MFMAQ(0, 1); __builtin_amdgcn_s_setprio(0);
  // ---- q2: re-read b-pair0; stage A-h0(t+2) ----
  READ_B(0);
  if constexpr (SA) stage_chunk(Lc, gA0, t + 2, tid);
  vmwait<V2>(); barf();
  __builtin_amdgcn_s_setprio(1); MFMAQ(1, 0); __builtin_amdgcn_s_setprio(0);
  // ---- q3: re-read b-pair1; stage A-h1(t+2) ----
  READ_B(1);
  if constexpr (SA) stage_chunk(Lc + 16384, gA1, t + 2, tid);
  vmwait<V3>(); barf();
  __builtin_amdgcn_s_setprio(1); MFMAQ(1, 1); __builtin_amdgcn_s_setprio(0);
}

extern "C" __global__ __launch_bounds__(512, 1)
void koleo_grammax(const unsigned short* __restrict__ xb, unsigned* __restrict__ maxenc) {
  __shared__ char lds[131072];   // 2 dbuf x (A 32KB + B 32KB); 1 block/CU

  const int tid  = threadIdx.x;
  const int lane = tid & 63;
  const int wid  = tid >> 6;
  const int wr   = wid >> 2;     // 0..1: rows wr*128..+127
  const int wc   = wid & 3;      // 0..3: cols wc*64..+63
  const int lr   = lane & 15;
  const int lg   = lane >> 4;

  // XCD-aware bijective swizzle (528 % 8 == 0)
  const int bid = (blockIdx.x % 8) * (NBLK / 8) + blockIdx.x / 8;
  // upper-triangle decode (ti <= tj)
  int ti = (int)((2.0f * NT + 1.0f -
                  sqrtf((float)((2 * NT + 1) * (2 * NT + 1) - 8 * bid))) * 0.5f);
  while ((ti + 1) * NT - ((ti + 1) * ti) / 2 <= bid) ++ti;
  while (ti * NT - (ti * (ti - 1)) / 2 > bid) --ti;
  const int tj = ti + (bid - (ti * NT - (ti * (ti - 1)) / 2));

  const int rowBase = ti * BM;
  const int colBase = tj * BM;
  const bool diag = (ti == tj);

  const char* xbb = (const char*)xb;
  const char* gA0 = xbb + (size_t)rowBase * 2048;
  const char* gA1 = xbb + (size_t)(rowBase + 128) * 2048;
  const char* gB0 = xbb + (size_t)colBase * 2048;
  const char* gB1 = xbb + (size_t)(colBase + 128) * 2048;
  char* L0 = lds;
  char* L1 = lds + 65536;

  f32x4  acc[8][4] = {};
  bf16x8 aF[8][2];
  bf16x8 bF[2][2];

  // prologue: issue order defines the vmcnt arithmetic
  stage_chunk(L0,         gA0, 0, tid);
  stage_chunk(L0 + 16384, gA1, 0, tid);
  stage_chunk(L0 + 32768, gB0, 0, tid);
  stage_chunk(L0 + 49152, gB1, 0, tid);
  stage_chunk(L1,         gA0, 1, tid);
  stage_chunk(L1 + 16384, gA1, 1, tid);
  vmwait<4>();   // all of K-tile 0 complete (4 newest = A-h(1) pair)
  barf();

#pragma unroll 1
  for (int t2 = 0; t2 < 14; t2 += 2) {
    ktile<true, true, 6, 6, 6, 6>(t2,     L0, L1, gA0, gA1, gB0, gB1, tid, lane, wr, wc, aF, bF, acc);
    ktile<true, true, 6, 6, 6, 6>(t2 + 1, L1, L0, gA0, gA1, gB0, gB1, tid, lane, wr, wc, aF, bF, acc);
  }
  // tail: t=14 stages only B(15); t=15 stages nothing
  ktile<true,  false, 6, 6, 6, 2>(14, L0, L1, gA0, gA1, gB0, gB1, tid, lane, wr, wc, aF, bF, acc);
  ktile<false, false, 0, 0, 0, 0>(15, L1, L0, gA0, gA1, gB0, gB1, tid, lane, wr, wc, aF, bF, acc);

  // ---- epilogue: per-row / per-col max with diagonal mask ----
  __syncthreads();                      // full drain; LDS reused below
  unsigned* smaxr = (unsigned*)lds;           // [256]
  unsigned* smaxc = (unsigned*)(lds + 1024);  // [256]
  if (tid < 256) { smaxr[tid] = 0u; smaxc[tid] = 0u; }
  __syncthreads();

#pragma unroll
  for (int m = 0; m < 8; ++m) {
#pragma unroll
    for (int r = 0; r < 4; ++r) {
      const int lrow = wr * 128 + m * 16 + lg * 4 + r;  // C/D: row=(lane>>4)*4+reg
      const int grow = rowBase + lrow;
      float mx = -2.0f;
#pragma unroll
      for (int n = 0; n < 4; ++n) {
        float v = acc[m][n][r];
        const int gcol = colBase + wc * 64 + n * 16 + lr;  // C/D: col=lane&15
        if (grow == gcol) v = -2.0f;                        // mask self-similarity
        mx = fmaxf(mx, v);
      }
#pragma unroll
      for (int off = 1; off < 16; off <<= 1) mx = fmaxf(mx, __shfl_xor(mx, off));
      if (lr == 0) atomicMax(&smaxr[lrow], encf(mx));
    }
  }
  if (!diag) {  // off-diagonal tiles: rows/cols disjoint, no mask needed
#pragma unroll
    for (int n = 0; n < 4; ++n) {
      const int lcol = wc * 64 + n * 16 + lr;
      float mx = -2.0f;
#pragma unroll
      for (int m = 0; m < 8; ++m)
#pragma unroll
        for (int r = 0; r < 4; ++r) mx = fmaxf(mx, acc[m][n][r]);
      mx = fmaxf(mx, __shfl_xor(mx, 16));
      mx = fmaxf(mx, __shfl_xor(mx, 32));
      if (lg == 0) atomicMax(&smaxc[lcol], encf(mx));
    }
  }
  __syncthreads();
  if (tid < 256) {
    atomicMax(&maxenc[rowBase + tid], smaxr[tid]);
    if (!diag) atomicMax(&maxenc[colBase + tid], smaxc[tid]);
  }
}

// ---------------- Kernel C: loss reduction ----------------
extern "C" __global__ __launch_bounds__(256)
void koleo_loss(const unsigned* __restrict__ maxenc, float* __restrict__ out) {
  const int tid = threadIdx.x;
  float sum = 0.0f;
  for (int i = tid; i < NROWS; i += 256) {
    const unsigned u    = maxenc[i];
    const unsigned bits = (u & 0x80000000u) ? (u & 0x7FFFFFFFu) : ~u;
    const float m = __uint_as_float(bits);
    const float d = sqrtf(fmaxf(2.0f - 2.0f * m, 0.0f)) + EPSF;  // ||x_i - x_nn|| + eps
    sum += logf(d + EPSF);
  }
#pragma unroll
  for (int off = 32; off > 0; off >>= 1) sum += __shfl_down(sum, off);
  __shared__ float wsum[4];
  if ((tid & 63) == 0) wsum[tid >> 6] = sum;
  __syncthreads();
  if (tid == 0) out[0] = -(wsum[0] + wsum[1] + wsum[2] + wsum[3]) / (float)NROWS;
}

extern "C" void kernel_launch(void* const* d_in, const int* in_sizes, int n_in,
                              void* d_out, int out_size, void* d_ws, size_t ws_size,
                              hipStream_t stream) {
  const float* in = (const float*)d_in[0];
  unsigned short* xb = (unsigned short*)d_ws;                                  // 16 MB bf16 x
  unsigned* maxenc   = (unsigned*)((char*)d_ws + (size_t)NROWS * DIM * 2);     // 32 KB
  float* out = (float*)d_out;

  hipLaunchKernelGGL(koleo_norm,    dim3(NROWS), dim3(256), 0, stream, in, xb, maxenc);
  hipLaunchKernelGGL(koleo_grammax, dim3(NBLK),  dim3(512), 0, stream, xb, maxenc);
  hipLaunchKernelGGL(koleo_loss,    dim3(1),     dim3(256), 0, stream, maxenc, out);
}

// Round 5
// 116.564 us; speedup vs baseline: 2.4783x; 2.0497x over previous
//
#include <hip/hip_runtime.h>

#define NROWS 8192
#define DIM   1024
#define EPSF  1e-8f

typedef __attribute__((ext_vector_type(4))) float f32x4;
typedef __attribute__((ext_vector_type(8))) short bf16x8;

typedef __attribute__((address_space(1))) void g_void;
typedef __attribute__((address_space(3))) void l_void;

__device__ __forceinline__ void async_copy16(void* lds, const void* g) {
  __builtin_amdgcn_global_load_lds((g_void*)const_cast<void*>(g), (l_void*)lds, 16, 0, 0);
}

__device__ __forceinline__ unsigned short f2bf(float f) {
  union { float f; unsigned u; } c; c.f = f;
  unsigned u = c.u;
  u += 0x7FFFu + ((u >> 16) & 1u);   // round-to-nearest-even
  return (unsigned short)(u >> 16);
}

__device__ __forceinline__ unsigned encf(float f) {
  const unsigned bits = __float_as_uint(f);
  return (bits & 0x80000000u) ? ~bits : (bits | 0x80000000u);
}

template<int N> __device__ __forceinline__ void vmwait() {
  if constexpr (N == 6)      asm volatile("s_waitcnt vmcnt(6)" ::: "memory");
  else if constexpr (N == 4) asm volatile("s_waitcnt vmcnt(4)" ::: "memory");
  else if constexpr (N == 2) asm volatile("s_waitcnt vmcnt(2)" ::: "memory");
  else                       asm volatile("s_waitcnt vmcnt(0)" ::: "memory");
}
__device__ __forceinline__ void barf() {
  __builtin_amdgcn_s_barrier();
  asm volatile("" ::: "memory");
}

// ---------------- Kernel A: row L2-normalize, cast to bf16, init maxenc ----------------
extern "C" __global__ __launch_bounds__(256)
void koleo_norm(const float* __restrict__ in, unsigned short* __restrict__ xb,
                unsigned* __restrict__ maxenc) {
  const int row = blockIdx.x;
  const int tid = threadIdx.x;
  const float4 v = reinterpret_cast<const float4*>(in + (size_t)row * DIM)[tid];
  float ss = v.x * v.x + v.y * v.y + v.z * v.z + v.w * v.w;
#pragma unroll
  for (int off = 32; off > 0; off >>= 1) ss += __shfl_down(ss, off);
  __shared__ float wsum[4];
  if ((tid & 63) == 0) wsum[tid >> 6] = ss;
  __syncthreads();
  const float total = wsum[0] + wsum[1] + wsum[2] + wsum[3];
  const float scale = 1.0f / (sqrtf(total) + EPSF);
  ushort4 o;
  o.x = f2bf(v.x * scale); o.y = f2bf(v.y * scale);
  o.z = f2bf(v.z * scale); o.w = f2bf(v.w * scale);
  reinterpret_cast<ushort4*>(xb + (size_t)row * DIM)[tid] = o;
  if (row < NROWS / 256) maxenc[row * 256 + tid] = 0u;  // enc(any real dot) > 0
}

// ---------------- Kernel B: triangle Gram-max, 256x128 tile, 4-phase pipeline ----------------
#define BMR 256
#define BNC 128
#define BK  64
#define NTR (NROWS / BMR)                 // 32 row-tiles
#define NBLK 1056                         // sum_{r<32} (64 - 2r) blocks with c >= 2r
#define NKT (DIM / BK)                    // 16 K-tiles

// stage one 16KB chunk (128 rows x 128B), XOR-swizzled source so LDS holds
// LDS[o] = logical[o ^ ((row&7)<<4)] with linear gload_lds destination
__device__ __forceinline__ void stage_chunk(char* dst, const char* gbase, int ktile, int tid) {
#pragma unroll
  for (int l = 0; l < 2; ++l) {
    const int o  = l * 8192 + tid * 16;
    const int so = o ^ (((o >> 7) & 7) << 4);
    async_copy16(dst + o, gbase + (size_t)(so >> 7) * 2048 + ktile * 128 + (so & 127));
  }
}

#define MFMAQ(MH, NH)                                                                 \
  {                                                                                   \
    _Pragma("unroll")                                                                 \
    for (int kk = 0; kk < 2; ++kk)                                                    \
      _Pragma("unroll")                                                               \
      for (int mm = 0; mm < 2; ++mm)                                                  \
        _Pragma("unroll")                                                             \
        for (int nn = 0; nn < 2; ++nn)                                                \
          acc[(MH)*2 + mm][(NH)*2 + nn] = __builtin_amdgcn_mfma_f32_16x16x32_bf16(    \
              aF[(MH)*2 + mm][kk], bF[nn][kk], acc[(MH)*2 + mm][(NH)*2 + nn],         \
              0, 0, 0);                                                               \
  }

#define READ_A(MH)                                                                    \
  _Pragma("unroll")                                                                   \
  for (int mm = 0; mm < 2; ++mm)                                                      \
    _Pragma("unroll")                                                                 \
    for (int kk = 0; kk < 2; ++kk)                                                    \
      aF[(MH)*2 + mm][kk] = *(const bf16x8*)(Lc +                                     \
          (((wr * 64 + ((MH)*2 + mm) * 16 + lr) * 128 + kk * 64 + lg * 16) ^ xr));

#define READ_B(NH)                                                                    \
  _Pragma("unroll")                                                                   \
  for (int nn = 0; nn < 2; ++nn)                                                      \
    _Pragma("unroll")                                                                 \
    for (int kk = 0; kk < 2; ++kk)                                                    \
      bF[nn][kk] = *(const bf16x8*)(Lc + 32768 +                                      \
          (((wc * 64 + ((NH)*2 + nn) * 16 + lr) * 128 + kk * 64 + lg * 16) ^ xr));

// Per K-tile t (reads Lc): q0 stages B(t+1)->Ln, q2/q3 stage A(t+2)->Lc.
// All A(t) reads done by q1 (before q2's stage issue into Lc's A region).
// The ONLY correctness wait is q3's vmcnt(V3): it guarantees tile t+1's
// A (staged q2/q3 of t-1, older) and B (staged q0(t), 4 newer loads follow)
// BEFORE the q0(t+1) reads execute. V3=4 keeps A(t+2)'s 4 loads in flight.
template<bool SB, bool SA, int V3>
__device__ __forceinline__ void ktile(int t, char* Lc, char* Ln,
    const char* gA0, const char* gA1, const char* gB,
    int tid, int lane, int wr, int wc,
    bf16x8 (&aF)[4][2], bf16x8 (&bF)[2][2], f32x4 (&acc)[4][4]) {
  const int lr = lane & 15, lg = lane >> 4;
  const int xr = (lane & 7) << 4;
  // ---- q0: read aF[0..1] + bF p0; stage B(t+1) ----
  READ_A(0); READ_B(0);
  if constexpr (SB) stage_chunk(Ln + 32768, gB, t + 1, tid);
  barf();
  __builtin_amdgcn_s_setprio(1); MFMAQ(0, 0); __builtin_amdgcn_s_setprio(0);
  // ---- q1: read aF[2..3] + bF p1 ----
  READ_A(1); READ_B(1);
  barf();
  __builtin_amdgcn_s_setprio(1); MFMAQ(0, 1); __builtin_amdgcn_s_setprio(0);
  // ---- q2: re-read bF p0; stage A-h0(t+2) (A(t) reads all done by q1 barrier) ----
  READ_B(0);
  if constexpr (SA) stage_chunk(Lc, gA0, t + 2, tid);
  barf();
  __builtin_amdgcn_s_setprio(1); MFMAQ(1, 0); __builtin_amdgcn_s_setprio(0);
  // ---- q3: re-read bF p1; stage A-h1(t+2); wait covers NEXT tile's q0 reads ----
  READ_B(1);
  if constexpr (SA) stage_chunk(Lc + 16384, gA1, t + 2, tid);
  vmwait<V3>(); barf();
  __builtin_amdgcn_s_setprio(1); MFMAQ(1, 1); __builtin_amdgcn_s_setprio(0);
}

extern "C" __global__ __launch_bounds__(512)
void koleo_grammax(const unsigned short* __restrict__ xb, unsigned* __restrict__ maxenc) {
  __shared__ char lds[98304];   // 2 dbuf x (A 32KB + B 16KB)

  const int tid  = threadIdx.x;
  const int lane = tid & 63;
  const int wid  = tid >> 6;
  const int wr   = wid >> 1;     // 0..3: rows wr*64..+63
  const int wc   = wid & 1;      // 0..1: cols wc*64..+63
  const int lr   = lane & 15;
  const int lg   = lane >> 4;

  // XCD-aware bijective swizzle (1056 % 8 == 0)
  const int bid = (blockIdx.x % 8) * (NBLK / 8) + blockIdx.x / 8;
  // decode (r, c) with c >= 2r from bid; S(r) = r*(65-r)
  int r = (int)((65.0f - sqrtf((float)(4225 - 4 * bid))) * 0.5f);
  while ((r + 1) * (65 - (r + 1)) <= bid) ++r;
  while (r * (65 - r) > bid) --r;
  const int c = 2 * r + (bid - r * (65 - r));

  const int rowBase = r * BMR;
  const int colBase = c * BNC;
  const bool colDiag = (c == 2 * r) || (c == 2 * r + 1);  // cols subset of rows

  const char* xbb = (const char*)xb;
  const char* gA0 = xbb + (size_t)rowBase * 2048;           // rows 0..127
  const char* gA1 = xbb + (size_t)(rowBase + 128) * 2048;   // rows 128..255
  const char* gB  = xbb + (size_t)colBase * 2048;           // 128 col-rows
  char* L0 = lds;
  char* L1 = lds + 49152;

  f32x4  acc[4][4] = {};
  bf16x8 aF[4][2];
  bf16x8 bF[2][2];

  // prologue: A(0),B(0)->L0 ; A(1)->L1 ; (B(1) staged at q0(0))
  stage_chunk(L0,         gA0, 0, tid);
  stage_chunk(L0 + 16384, gA1, 0, tid);
  stage_chunk(L0 + 32768, gB,  0, tid);
  stage_chunk(L1,         gA0, 1, tid);
  stage_chunk(L1 + 16384, gA1, 1, tid);
  vmwait<4>();   // A(0)+B(0) done; A(1)'s 4 loads in flight
  barf();

#pragma unroll 1
  for (int t2 = 0; t2 < 14; t2 += 2) {
    ktile<true, true, 4>(t2,     L0, L1, gA0, gA1, gB, tid, lane, wr, wc, aF, bF, acc);
    ktile<true, true, 4>(t2 + 1, L1, L0, gA0, gA1, gB, tid, lane, wr, wc, aF, bF, acc);
  }
  // t=14: stage B(15) only; V3=0 (no newer loads cover B(15)). t=15: nothing.
  ktile<true,  false, 0>(14, L0, L1, gA0, gA1, gB, tid, lane, wr, wc, aF, bF, acc);
  ktile<false, false, 0>(15, L1, L0, gA0, gA1, gB, tid, lane, wr, wc, aF, bF, acc);

  // ---- epilogue: per-row / per-col max with diagonal mask ----
  __syncthreads();
  unsigned* smaxr = (unsigned*)lds;           // [256]
  unsigned* smaxc = (unsigned*)(lds + 1024);  // [128]
  if (tid < 256) smaxr[tid] = 0u;
  if (tid < 128) smaxc[tid] = 0u;
  __syncthreads();

#pragma unroll
  for (int m = 0; m < 4; ++m) {
#pragma unroll
    for (int rr = 0; rr < 4; ++rr) {
      const int lrow = wr * 64 + m * 16 + lg * 4 + rr;  // C/D: row=(lane>>4)*4+reg
      const int grow = rowBase + lrow;
      float mx = -2.0f;
#pragma unroll
      for (int n = 0; n < 4; ++n) {
        float v = acc[m][n][rr];
        const int gcol = colBase + wc * 64 + n * 16 + lr;  // C/D: col=lane&15
        if (grow == gcol) v = -2.0f;                        // mask self-similarity
        mx = fmaxf(mx, v);
      }
#pragma unroll
      for (int off = 1; off < 16; off <<= 1) mx = fmaxf(mx, __shfl_xor(mx, off));
      if (lr == 0) atomicMax(&smaxr[lrow], encf(mx));
    }
  }
  if (!colDiag) {  // symmetric fold: col j's max over this block's rows
#pragma unroll
    for (int n = 0; n < 4; ++n) {
      const int lcol = wc * 64 + n * 16 + lr;
      float mx = -2.0f;
#pragma unroll
      for (int m = 0; m < 4; ++m)
#pragma unroll
        for (int rr = 0; rr < 4; ++rr) mx = fmaxf(mx, acc[m][n][rr]);
      mx = fmaxf(mx, __shfl_xor(mx, 16));
      mx = fmaxf(mx, __shfl_xor(mx, 32));
      if (lg == 0) atomicMax(&smaxc[lcol], encf(mx));
    }
  }
  __syncthreads();
  if (tid < 256) atomicMax(&maxenc[rowBase + tid], smaxr[tid]);
  if (tid < 128 && !colDiag) atomicMax(&maxenc[colBase + tid], smaxc[tid]);
}

// ---------------- Kernel C: loss reduction ----------------
extern "C" __global__ __launch_bounds__(256)
void koleo_loss(const unsigned* __restrict__ maxenc, float* __restrict__ out) {
  const int tid = threadIdx.x;
  float sum = 0.0f;
  for (int i = tid; i < NROWS; i += 256) {
    const unsigned u    = maxenc[i];
    const unsigned bits = (u & 0x80000000u) ? (u & 0x7FFFFFFFu) : ~u;
    const float m = __uint_as_float(bits);
    const float d = sqrtf(fmaxf(2.0f - 2.0f * m, 0.0f)) + EPSF;  // ||x_i - x_nn|| + eps
    sum += logf(d + EPSF);
  }
#pragma unroll
  for (int off = 32; off > 0; off >>= 1) sum += __shfl_down(sum, off);
  __shared__ float wsum[4];
  if ((tid & 63) == 0) wsum[tid >> 6] = sum;
  __syncthreads();
  if (tid == 0) out[0] = -(wsum[0] + wsum[1] + wsum[2] + wsum[3]) / (float)NROWS;
}

extern "C" void kernel_launch(void* const* d_in, const int* in_sizes, int n_in,
                              void* d_out, int out_size, void* d_ws, size_t ws_size,
                              hipStream_t stream) {
  const float* in = (const float*)d_in[0];
  unsigned short* xb = (unsigned short*)d_ws;                                  // 16 MB bf16 x
  unsigned* maxenc   = (unsigned*)((char*)d_ws + (size_t)NROWS * DIM * 2);     // 32 KB
  float* out = (float*)d_out;

  hipLaunchKernelGGL(koleo_norm,    dim3(NROWS), dim3(256), 0, stream, in, xb, maxenc);
  hipLaunchKernelGGL(koleo_grammax, dim3(NBLK),  dim3(512), 0, stream, xb, maxenc);
  hipLaunchKernelGGL(koleo_loss,    dim3(1),     dim3(256), 0, stream, maxenc, out);
}